// Round 15
// baseline (107.542 us; speedup 1.0000x reference)
//
#include <hip/hip_runtime.h>

#define NEGF -9e15f

typedef __attribute__((ext_vector_type(8))) unsigned short u16x8;
typedef __attribute__((ext_vector_type(8))) short          s16x8;
typedef __attribute__((ext_vector_type(4))) float          f32x4;

// ---------- bf16 helpers (RTN-even) ----------
__device__ __forceinline__ unsigned short f2bf(float x) {
  union { float f; unsigned int u; } c; c.f = x;
  unsigned int r = c.u + 0x7fffu + ((c.u >> 16) & 1u);
  return (unsigned short)(r >> 16);
}
__device__ __forceinline__ float bf2f(unsigned short v) {
  union { float f; unsigned int u; } c; c.u = ((unsigned int)v) << 16;
  return c.f;
}

// ---------- async global->LDS, 16B per lane (wave-uniform LDS base) ----------
__device__ __forceinline__ void gload16(const void* g, void* l) {
  __builtin_amdgcn_global_load_lds(
      (const __attribute__((address_space(1))) unsigned int*)g,
      (__attribute__((address_space(3))) unsigned int*)l, 16, 0, 0);
}

// ================= prep kernels (fallback path) =================
__global__ __launch_bounds__(256) void cvt2_bf16(
    const float* __restrict__ a, const float* __restrict__ b,
    unsigned short* __restrict__ oa, unsigned short* __restrict__ ob)
{
  const int bid = blockIdx.x;
  const float* in = (bid < 4096) ? a : b;
  unsigned short* out = (bid < 4096) ? oa : ob;
  const int i = ((bid & 4095) * 256 + threadIdx.x) * 4;
  const float4 v = *(const float4*)(in + i);
  ushort4 o;
  o.x = f2bf(v.x); o.y = f2bf(v.y); o.z = f2bf(v.z); o.w = f2bf(v.w);
  *(ushort4*)(out + i) = o;
}

__global__ __launch_bounds__(256) void prep_w(
    const float* __restrict__ Wq, const float* __restrict__ Wk,
    const float* __restrict__ Wo, const float* __restrict__ Wv,
    unsigned short* __restrict__ Wall, unsigned short* __restrict__ Wo_bf,
    unsigned short* __restrict__ Wvt_bf)
{
  __shared__ float tile[32][33];
  const int bid = blockIdx.x;
  if (bid < 3072) {
    const int i = ((bid & 1023) * 256 + threadIdx.x) * 4;
    const float* in;
    unsigned short* out;
    float sc = 1.f;
    if (bid < 1024)      { in = Wq; out = Wall;           sc = 0.125f; }
    else if (bid < 2048) { in = Wk; out = Wall + 1048576; }
    else                 { in = Wo; out = Wo_bf; }
    const float4 v = *(const float4*)(in + i);
    ushort4 o;
    o.x = f2bf(v.x * sc); o.y = f2bf(v.y * sc);
    o.z = f2bf(v.z * sc); o.w = f2bf(v.w * sc);
    *(ushort4*)(out + i) = o;
  } else {
    const int j = bid - 3072;
    const int bc = (j & 31) * 32, br = (j >> 5) * 32;
    const int tx = threadIdx.x & 31, ty8 = threadIdx.x >> 5;
    #pragma unroll
    for (int jj = 0; jj < 32; jj += 8)
      tile[ty8 + jj][tx] = Wv[(size_t)(br + ty8 + jj) * 1024 + bc + tx];
    __syncthreads();
    #pragma unroll
    for (int jj = 0; jj < 32; jj += 8)
      Wvt_bf[(size_t)(bc + ty8 + jj) * 1024 + br + tx] = f2bf(tile[tx][ty8 + jj]);
  }
}

__global__ __launch_bounds__(256) void prep_bias(
    const float* __restrict__ bq, const float* __restrict__ bk,
    const float* __restrict__ Wo, const float* __restrict__ bv,
    float* __restrict__ ball)
{
  const int bid = blockIdx.x;
  if (bid < 4) {
    const int i = bid * 256 + threadIdx.x;
    ball[i]        = 0.125f * bq[i];
    ball[1024 + i] = bk[i];
  } else {
    const int g    = (bid - 4) * 4 + (threadIdx.x >> 6);
    const int lane = threadIdx.x & 63;
    float acc = 0.f;
    for (int f = lane; f < 1024; f += 64)
      acc = fmaf(Wo[(size_t)g * 1024 + f], bv[f], acc);
    #pragma unroll
    for (int off = 32; off > 0; off >>= 1) acc += __shfl_down(acc, off);
    if (lane == 0) ball[2048 + g] = acc;
  }
}

__global__ __launch_bounds__(256) void mb_prep(
    const int* __restrict__ adj, const float* __restrict__ lab,
    float* __restrict__ mb)
{
  const int i = (blockIdx.x * 256 + threadIdx.x) * 4;
  const int4   a = *(const int4*)(adj + i);
  const float4 l = *(const float4*)(lab + i);
  float4 o;
  o.x = a.x > 0 ? l.x : NEGF;
  o.y = a.y > 0 ? l.y : NEGF;
  o.z = a.z > 0 ? l.z : NEGF;
  o.w = a.w > 0 ? l.w : NEGF;
  *(float4*)(mb + i) = o;
}

// ================= fused prep (big-ws path) =================
__global__ __launch_bounds__(256) void prep_all(
    const float* __restrict__ obj, const float* __restrict__ cross,
    const float* __restrict__ Wq, const float* __restrict__ Wk,
    const float* __restrict__ Wo, const float* __restrict__ Wv,
    const float* __restrict__ bq, const float* __restrict__ bk,
    const float* __restrict__ bv,
    const int* __restrict__ adj, const float* __restrict__ lab,
    unsigned short* __restrict__ obj_bf, unsigned short* __restrict__ cross_bf,
    unsigned short* __restrict__ Wall, unsigned short* __restrict__ Wo_bf,
    unsigned short* __restrict__ Wvt_bf,
    float* __restrict__ ball, float* __restrict__ mb)
{
  __shared__ float tile[32][33];
  const int bid = blockIdx.x;
  if (bid < 8192) {
    const float* in = (bid < 4096) ? obj : cross;
    unsigned short* out = (bid < 4096) ? obj_bf : cross_bf;
    const int i = ((bid & 4095) * 256 + threadIdx.x) * 4;
    const float4 v = *(const float4*)(in + i);
    ushort4 o;
    o.x = f2bf(v.x); o.y = f2bf(v.y); o.z = f2bf(v.z); o.w = f2bf(v.w);
    *(ushort4*)(out + i) = o;
  } else if (bid < 11264) {
    const int wb = bid - 8192;
    const int i = ((wb & 1023) * 256 + threadIdx.x) * 4;
    const float* in;
    unsigned short* out;
    float sc = 1.f;
    if (wb < 1024)      { in = Wq; out = Wall;           sc = 0.125f; }
    else if (wb < 2048) { in = Wk; out = Wall + 1048576; }
    else                { in = Wo; out = Wo_bf; }
    const float4 v = *(const float4*)(in + i);
    ushort4 o;
    o.x = f2bf(v.x * sc); o.y = f2bf(v.y * sc);
    o.z = f2bf(v.z * sc); o.w = f2bf(v.w * sc);
    *(ushort4*)(out + i) = o;
  } else if (bid < 12288) {
    const int j = bid - 11264;
    const int bc = (j & 31) * 32, br = (j >> 5) * 32;
    const int tx = threadIdx.x & 31, ty8 = threadIdx.x >> 5;
    #pragma unroll
    for (int jj = 0; jj < 32; jj += 8)
      tile[ty8 + jj][tx] = Wv[(size_t)(br + ty8 + jj) * 1024 + bc + tx];
    __syncthreads();
    #pragma unroll
    for (int jj = 0; jj < 32; jj += 8)
      Wvt_bf[(size_t)(bc + ty8 + jj) * 1024 + br + tx] = f2bf(tile[tx][ty8 + jj]);
  } else if (bid < 12548) {
    const int pb = bid - 12288;
    if (pb < 4) {
      const int i = pb * 256 + threadIdx.x;
      ball[i]        = 0.125f * bq[i];
      ball[1024 + i] = bk[i];
    } else {
      const int g    = (pb - 4) * 4 + (threadIdx.x >> 6);
      const int lane = threadIdx.x & 63;
      float acc = 0.f;
      for (int f = lane; f < 1024; f += 64)
        acc = fmaf(Wo[(size_t)g * 1024 + f], bv[f], acc);
      #pragma unroll
      for (int off = 32; off > 0; off >>= 1) acc += __shfl_down(acc, off);
      if (lane == 0) ball[2048 + g] = acc;
    }
  } else {
    const int i = ((bid - 12548) * 256 + threadIdx.x) * 4;
    const int4   a = *(const int4*)(adj + i);
    const float4 l = *(const float4*)(lab + i);
    float4 o;
    o.x = a.x > 0 ? l.x : NEGF;
    o.y = a.y > 0 ? l.y : NEGF;
    o.z = a.z > 0 ? l.z : NEGF;
    o.w = a.w > 0 ? l.w : NEGF;
    *(float4*)(mb + i) = o;
  }
}

// ---------------------------------------------------------------
// Wov = Wo @ Wv (1024^3), m97-style staging, 64x64 tiles -> 256 blocks.
// ---------------------------------------------------------------
__global__ __launch_bounds__(256, 3) void gemm_wov(
    const unsigned short* __restrict__ A,
    const unsigned short* __restrict__ Bw,
    unsigned short* __restrict__ Cout)
{
  __shared__ unsigned short Asm[64 * 64];
  __shared__ unsigned short Bsm[64 * 64];
  const int t = threadIdx.x;
  const int lane = t & 63, w = t >> 6;
  const int wm = w >> 1, wn = w & 1;
  const int bm = blockIdx.y * 64, bn = blockIdx.x * 64;

  const int skel = (lane & 7) * 8;
  const int fr = lane & 15, kf = (lane >> 4) * 8;

  f32x4 acc[2][2] = {};

  for (int k0 = 0; k0 < 1024; k0 += 64) {
    if (k0) __syncthreads();
    #pragma unroll
    for (int c = 0; c < 2; ++c) {
      const int row = c * 32 + w * 8 + (lane >> 3);
      gload16(A  + (size_t)(bm + row) * 1024 + k0 + skel, (char*)Asm + c * 4096 + w * 1024);
      gload16(Bw + (size_t)(bn + row) * 1024 + k0 + skel, (char*)Bsm + c * 4096 + w * 1024);
    }
    __syncthreads();
    #pragma unroll
    for (int kk = 0; kk < 2; ++kk) {
      s16x8 af[2], bf[2];
      #pragma unroll
      for (int fm = 0; fm < 2; ++fm)
        af[fm] = *(const s16x8*)&Asm[(wm * 32 + fm * 16 + fr) * 64 + kk * 32 + kf];
      #pragma unroll
      for (int fn = 0; fn < 2; ++fn)
        bf[fn] = *(const s16x8*)&Bsm[(wn * 32 + fn * 16 + fr) * 64 + kk * 32 + kf];
      #pragma unroll
      for (int fm = 0; fm < 2; ++fm)
        #pragma unroll
        for (int fn = 0; fn < 2; ++fn)
          acc[fm][fn] = __builtin_amdgcn_mfma_f32_16x16x32_bf16(af[fm], bf[fn], acc[fm][fn], 0, 0, 0);
    }
  }

  const int rg = (lane >> 4) * 4;
  #pragma unroll
  for (int fm = 0; fm < 2; ++fm)
    #pragma unroll
    for (int fn = 0; fn < 2; ++fn) {
      const int col = bn + wn * 32 + fn * 16 + fr;
      #pragma unroll
      for (int r = 0; r < 4; ++r) {
        const int row = bm + wm * 32 + fm * 16 + rg + r;
        Cout[(size_t)row * 1024 + col] = f2bf(acc[fm][fn][r]);
      }
    }
}

// ---------------------------------------------------------------
// Fused projection GEMM v3 + coalesced LDS-bounce epilogue (r14-identical).
// ---------------------------------------------------------------
__global__ __launch_bounds__(512, 2) void gemm_big(
    const unsigned short* __restrict__ objA,
    const unsigned short* __restrict__ crossA,
    const unsigned short* __restrict__ Wall,   // [3072][1024]
    const float* __restrict__ ball,            // [3072]
    unsigned short* __restrict__ Qo,           // [4096][1024]
    unsigned short* __restrict__ Ko,           // [4096][1024]
    unsigned short* __restrict__ VWt)          // [B*1024][256]
{
  __shared__ __align__(16) char smem[131072];
  const int t = threadIdx.x;
  const int wid = t >> 6, lane = t & 63;
  const int wm = wid >> 2, wn = wid & 3;
  const int fr = lane & 15, grp = lane >> 4;

  const int bid = blockIdx.x;
  const int xcd = bid & 7, j = bid >> 3;
  const int bmi = (xcd >> 1) * 4 + j / 6;
  const int bni = (xcd & 1) * 6 + j % 6;
  const int bm = bmi * 256, bn = bni * 256;
  const unsigned short* Ag = ((bni < 4) ? objA : crossA) + (size_t)bm * 1024;
  const unsigned short* Bg = Wall + (size_t)bn * 1024;

  const int r8 = lane >> 3, cb = (lane & 7) * 16;

  f32x4 acc[8][4] = {};
  s16x8 bfr[4][2];
  s16x8 aq[2][2];

  auto CH = [&](int buf, int isB, int q, int k0) {
    const int row = q * 64 + wid * 8 + r8;
    const int sc  = cb ^ ((row & 7) << 4);
    const unsigned short* src = isB ? Bg : Ag;
    gload16((const char*)(src + (size_t)row * 1024 + k0) + sc,
            smem + buf * 65536 + isB * 32768 + q * 8192 + wid * 1024);
  };

#define BAR() { asm volatile("" ::: "memory"); __builtin_amdgcn_s_barrier(); asm volatile("" ::: "memory"); }
#define RDB(BUF)                                                             \
  { _Pragma("unroll") for (int fn = 0; fn < 4; ++fn)                         \
      _Pragma("unroll") for (int kk = 0; kk < 2; ++kk) {                     \
        const int row = wn * 64 + fn * 16 + fr;                              \
        bfr[fn][kk] = *(const s16x8*)((BUF) + 32768 + row * 128 +            \
            ((kk * 64 + grp * 16) ^ ((row & 7) << 4)));                      \
      } }
#define RDA(BUF, P)                                                          \
  { _Pragma("unroll") for (int fm = 0; fm < 2; ++fm)                         \
      _Pragma("unroll") for (int kk = 0; kk < 2; ++kk) {                     \
        const int row = wm * 128 + (2 * (P) + fm) * 16 + fr;                 \
        aq[fm][kk] = *(const s16x8*)((BUF) + row * 128 +                     \
            ((kk * 64 + grp * 16) ^ ((row & 7) << 4)));                      \
      } }
#define MMQ(P)                                                               \
  { __builtin_amdgcn_s_setprio(1);                                           \
    _Pragma("unroll") for (int fm = 0; fm < 2; ++fm)                         \
      _Pragma("unroll") for (int fn = 0; fn < 4; ++fn) {                     \
        acc[2 * (P) + fm][fn] = __builtin_amdgcn_mfma_f32_16x16x32_bf16(     \
            aq[fm][0], bfr[fn][0], acc[2 * (P) + fm][fn], 0, 0, 0);          \
        acc[2 * (P) + fm][fn] = __builtin_amdgcn_mfma_f32_16x16x32_bf16(     \
            aq[fm][1], bfr[fn][1], acc[2 * (P) + fm][fn], 0, 0, 0);          \
      }                                                                      \
    __builtin_amdgcn_s_setprio(0); }
#define TILE4(BUF)                                                           \
  RDB(BUF); RDA(BUF, 0); BAR(); MMQ(0); BAR();                               \
  RDA(BUF, 1); BAR(); MMQ(1); BAR();                                         \
  RDA(BUF, 2); BAR(); MMQ(2); BAR();                                         \
  RDA(BUF, 3); BAR(); MMQ(3); BAR();

  CH(0, 1, 0, 0); CH(0, 1, 1, 0); CH(0, 1, 2, 0); CH(0, 1, 3, 0);
  CH(0, 0, 0, 0); CH(0, 0, 1, 0); CH(0, 0, 2, 0); CH(0, 0, 3, 0);
  CH(1, 1, 0, 64); CH(1, 1, 1, 64); CH(1, 1, 2, 64); CH(1, 1, 3, 64);
  CH(1, 0, 0, 64); CH(1, 0, 2, 64);

  #pragma unroll 2
  for (int kt = 0; kt < 14; ++kt) {
    const int cur = kt & 1;
    char* bufc = smem + cur * 65536;
    const int k1 = (kt + 1) * 64, k2 = (kt + 2) * 64;
    CH(cur ^ 1, 0, 1, k1);
    CH(cur ^ 1, 0, 3, k1);
    asm volatile("s_waitcnt vmcnt(8)" ::: "memory");
    BAR();
    RDB(bufc); RDA(bufc, 0);
    BAR(); MMQ(0); BAR();
    RDA(bufc, 1); CH(cur, 1, 0, k2); CH(cur, 1, 1, k2);
    BAR(); MMQ(1); BAR();
    RDA(bufc, 2); CH(cur, 1, 2, k2); CH(cur, 1, 3, k2);
    BAR(); MMQ(2); BAR();
    RDA(bufc, 3); CH(cur, 0, 0, k2); CH(cur, 0, 2, k2);
    BAR(); MMQ(3); BAR();
  }
  CH(1, 0, 1, 960); CH(1, 0, 3, 960);
  asm volatile("s_waitcnt vmcnt(8)" ::: "memory");
  BAR();
  TILE4(smem);
  asm volatile("s_waitcnt vmcnt(0)" ::: "memory");
  BAR();
  TILE4(smem + 65536);

#undef BAR
#undef RDB
#undef RDA
#undef MMQ
#undef TILE4

  // ---- epilogue: acc -> bf16 LDS image (swizzled) -> coalesced 16B stores ----
  __syncthreads();
  const int rg = grp * 4;
  const int mode = bn >> 10;                           // 0=Q 1=K 2=VW
  if (mode < 2) {
    #pragma unroll
    for (int fm = 0; fm < 8; ++fm)
      #pragma unroll
      for (int fn = 0; fn < 4; ++fn) {
        const int col = wn * 64 + fn * 16 + fr;
        const float bb = ball[bn + col];
        const int row0 = wm * 128 + fm * 16 + rg;
        #pragma unroll
        for (int r = 0; r < 4; ++r)
          *(unsigned short*)(smem + (row0 + r) * 512 +
              ((col * 2) ^ (((row0 + r) & 7) << 4))) = f2bf(acc[fm][fn][r] + bb);
      }
    __syncthreads();
    unsigned short* dst0 = (mode == 0) ? Qo : Ko;
    #pragma unroll
    for (int it = 0; it < 16; ++it) {
      const int row = it * 16 + wid * 2 + (lane >> 5);
      const int off = (lane & 31) * 16;
      *(u16x8*)((char*)(dst0 + (size_t)(bm + row) * 1024 + (bn & 1023)) + off)
          = *(const u16x8*)(smem + row * 512 + (off ^ ((row & 7) << 4)));
    }
  } else {
    #pragma unroll
    for (int fm = 0; fm < 8; ++fm)
      #pragma unroll
      for (int fn = 0; fn < 4; ++fn) {
        const int col = wn * 64 + fn * 16 + fr;
        const float bb = ball[bn + col];
        const int tok0 = wm * 128 + fm * 16 + rg;
        ushort4 u;
        u.x = f2bf(acc[fm][fn][0] + bb);
        u.y = f2bf(acc[fm][fn][1] + bb);
        u.z = f2bf(acc[fm][fn][2] + bb);
        u.w = f2bf(acc[fm][fn][3] + bb);
        *(ushort4*)(smem + col * 512 + ((tok0 * 2) ^ ((col & 7) << 4))) = u;
      }
    __syncthreads();
    const int bidx = bm >> 8;
    #pragma unroll
    for (int it = 0; it < 16; ++it) {
      const int col = it * 16 + wid * 2 + (lane >> 5);
      const int off = (lane & 31) * 16;
      *(u16x8*)((char*)(VWt + ((size_t)bidx * 1024 + (bn & 1023) + col) * 256) + off)
          = *(const u16x8*)(smem + col * 512 + (off ^ ((col & 7) << 4)));
    }
  }
}

// ---------------------------------------------------------------
// MFMA attention v7 = v6 + setprio around MFMA clusters (T5, m191)
// + issue-late Pb stores (after PV + out). QK^T math unchanged.
// ---------------------------------------------------------------
__global__ __launch_bounds__(512, 4) void attn_mfma(
    const unsigned short* __restrict__ Qg,    // [B*256][1024] bf16, pre-scaled 1/8
    const unsigned short* __restrict__ Kg,    // [B*256][1024] bf16
    const unsigned short* __restrict__ VWt,   // [B*1024][256] bf16 ([b][h*64+d][k])
    const float* __restrict__ mb,             // [B][256][256] masked bias
    const float* __restrict__ bo,
    float* __restrict__ outp, unsigned short* __restrict__ Pb)
{
  const int t = threadIdx.x;
  const int wid = t >> 6, lane = t & 63;
  const int fr = lane & 15, grp = lane >> 4;
  const int bid = blockIdx.x;
  const int xcd = bid & 7, i = bid >> 3;     // i in [0,64)
  const int h    = i & 15;
  const int r2   = i >> 4;                   // [0,4)
  const int half = r2 & 1;
  const int b    = xcd * 2 + (r2 >> 1);
  const int q0 = half * 128 + wid * 16;

  __shared__ __align__(16) unsigned short Ks[256 * 64];    // 32 KB [k_row][d]
  __shared__ __align__(16) unsigned short VWs[64 * 256];   // 32 KB [d][k]

  // ---- DMA K slice (b,h) ----
  {
    const unsigned short* kb = Kg + (size_t)(b * 256) * 1024 + h * 64;
    const int colb = (lane & 7) * 16;
    #pragma unroll
    for (int c = 0; c < 4; ++c) {
      const int row = c * 64 + wid * 8 + (lane >> 3);
      const int sb  = colb ^ ((row & 7) << 4);
      gload16(kb + (size_t)row * 1024 + (sb >> 1), (char*)Ks + c * 8192 + wid * 1024);
    }
  }
  // ---- DMA VW slice (b,h) ----
  {
    const unsigned short* vwb = VWt + (size_t)(b * 16 + h) * 16384;
    const int xb = (lane & 31) * 16;
    #pragma unroll
    for (int c = 0; c < 4; ++c) {
      const int row = c * 16 + wid * 2 + (lane >> 5);
      const int sb  = xb ^ ((row & 7) << 4);
      gload16(vwb + row * 256 + (sb >> 1), (char*)VWs + c * 8192 + wid * 1024);
    }
  }

  // ---- Q B-frags + first mb batch (overlap DMA drain) ----
  const unsigned short* qp = Qg + ((size_t)(b * 256 + q0 + fr)) * 1024 + h * 64 + grp * 8;
  const s16x8 qf0 = *(const s16x8*)qp;
  const s16x8 qf1 = *(const s16x8*)(qp + 32);
  const float* mbp = mb + ((size_t)(b * 256 + q0 + fr)) * 256 + grp * 4;
  float4 mA[4], mB[4];
  #pragma unroll
  for (int i2 = 0; i2 < 4; ++i2) mA[i2] = *(const float4*)(mbp + i2 * 16);

  __syncthreads();   // drains DMA (vmcnt 0) -> Ks/VWs ready

  const int colA = (grp * 16) ^ ((fr & 7) << 4);

  f32x4 s[16];
  #pragma unroll
  for (int nf = 0; nf < 16; ++nf) s[nf] = (f32x4){0.f, 0.f, 0.f, 0.f};

  s16x8 kA[8], kB[8];
  float mx = -3e38f;

#define LOADK(KF, nb)                                                        \
  { _Pragma("unroll") for (int i2 = 0; i2 < 4; ++i2) {                       \
      const char* rp = (const char*)Ks + (((nb)*4 + i2) * 16 + fr) * 128;    \
      KF[2*i2]   = *(const s16x8*)(rp + colA);                               \
      KF[2*i2+1] = *(const s16x8*)(rp + (colA ^ 64)); } }
#define LOADB(KF, MF, nb)                                                    \
  { _Pragma("unroll") for (int i2 = 0; i2 < 4; ++i2) {                       \
      const char* rp = (const char*)Ks + (((nb)*4 + i2) * 16 + fr) * 128;    \
      KF[2*i2]   = *(const s16x8*)(rp + colA);                               \
      KF[2*i2+1] = *(const s16x8*)(rp + (colA ^ 64));                        \
      MF[i2]     = *(const float4*)(mbp + ((nb)*4 + i2) * 16); } }
#define MFMAB(KF, nb)                                                        \
  { __builtin_amdgcn_s_setprio(1);                                           \
    _Pragma("unroll") for (int i2 = 0; i2 < 4; ++i2) {                       \
      s[(nb)*4+i2] = __builtin_amdgcn_mfma_f32_16x16x32_bf16(KF[2*i2],   qf0, s[(nb)*4+i2], 0, 0, 0); \
      s[(nb)*4+i2] = __builtin_amdgcn_mfma_f32_16x16x32_bf16(KF[2*i2+1], qf1, s[(nb)*4+i2], 0, 0, 0); } \
    __builtin_amdgcn_s_setprio(0); }
#define MASKB(MF, nb)                                                        \
  { _Pragma("unroll") for (int i2 = 0; i2 < 4; ++i2) {                       \
      _Pragma("unroll") for (int r = 0; r < 4; ++r) {                        \
        const float m = ((const float*)&MF[i2])[r];                          \
        const float v = (m > -1e14f) ? s[(nb)*4+i2][r] + m : m;              \
        s[(nb)*4+i2][r] = v; mx = fmaxf(mx, v); } } }

  LOADK(kA, 0);     LOADB(kB, mB, 1); MFMAB(kA, 0);
  MASKB(mA, 0);     LOADB(kA, mA, 2); MFMAB(kB, 1);
  MASKB(mB, 1);     LOADB(kB, mB, 3); MFMAB(kA, 2);
  MASKB(mA, 2);     LOADB(kA, mA, 4); MFMAB(kB, 3);
  MASKB(mB, 3);     LOADB(kB, mB, 5); MFMAB(kA, 4);
  MASKB(mA, 4);     LOADB(kA, mA, 6); MFMAB(kB, 5);
  MASKB(mB, 5);     LOADB(kB, mB, 7); MFMAB(kA, 6);
  MASKB(mA, 6);     MFMAB(kB, 7);     MASKB(mB, 7);
#undef LOADK
#undef LOADB
#undef MFMAB
#undef MASKB

  // ---- softmax ----
  mx = fmaxf(mx, __shfl_xor(mx, 16));
  mx = fmaxf(mx, __shfl_xor(mx, 32));
  float sm = 0.f;
  #pragma unroll
  for (int nf = 0; nf < 16; ++nf)
    #pragma unroll
    for (int r = 0; r < 4; ++r) {
      const float e = __expf(s[nf][r] - mx);
      s[nf][r] = e;
      sm += e;
    }
  sm += __shfl_xor(sm, 16);
  sm += __shfl_xor(sm, 32);
  const float inv = 1.f / sm;

  // ---- pack P -> bf16 pairs ----
  uint2 u2[16];
  #pragma unroll
  for (int nf = 0; nf < 16; ++nf) {
    const unsigned lo = (unsigned)f2bf(s[nf][0] * inv) | ((unsigned)f2bf(s[nf][1] * inv) << 16);
    const unsigned hi = (unsigned)f2bf(s[nf][2] * inv) | ((unsigned)f2bf(s[nf][3] * inv) << 16);
    u2[nf] = make_uint2(lo, hi);
  }

  // ---- PV (setprio-wrapped MFMA clusters) ----
  f32x4 o[4];
  #pragma unroll
  for (int nf = 0; nf < 4; ++nf) o[nf] = (f32x4){0.f, 0.f, 0.f, 0.f};
  const int srcA = fr + ((grp & 1) << 5);
  const int srcB = srcA + 16;
  const int swz  = (fr & 7) << 4;
  const bool hiSel = (grp & 2);
  #pragma unroll
  for (int ks = 0; ks < 8; ++ks) {
    const int aLx = __shfl((int)u2[2 * ks].x,     srcA, 64);
    const int aLy = __shfl((int)u2[2 * ks].y,     srcA, 64);
    const int bLx = __shfl((int)u2[2 * ks].x,     srcB, 64);
    const int bLy = __shfl((int)u2[2 * ks].y,     srcB, 64);
    const int aHx = __shfl((int)u2[2 * ks + 1].x, srcA, 64);
    const int aHy = __shfl((int)u2[2 * ks + 1].y, srcA, 64);
    const int bHx = __shfl((int)u2[2 * ks + 1].x, srcB, 64);
    const int bHy = __shfl((int)u2[2 * ks + 1].y, srcB, 64);
    union { int4 i; s16x8 v; } pf;
    pf.i = hiSel ? make_int4(aHx, aHy, bHx, bHy) : make_int4(aLx, aLy, bLx, bLy);
    const int cbv = (ks * 64 + grp * 16) ^ swz;
    __builtin_amdgcn_s_setprio(1);
    #pragma unroll
    for (int nf = 0; nf < 4; ++nf) {
      const s16x8 vf = *(const s16x8*)((const char*)VWs + (nf * 16 + fr) * 512 + cbv);
      o[nf] = __builtin_amdgcn_mfma_f32_16x16x32_bf16(pf.v, vf, o[nf], 0, 0, 0);
    }
    __builtin_amdgcn_s_setprio(0);
  }

  // ---- out epilogue first (validated output issued earliest) ----
  #pragma unroll
  for (int nf = 0; nf < 4; ++nf) {
    const float bb = bo[h * 64 + nf * 16 + fr];
    #pragma unroll
    for (int r = 0; r < 4; ++r)
      outp[((size_t)b * 256 + q0 + grp * 4 + r) * 1024 + h * 64 + nf * 16 + fr]
          = o[nf][r] + bb;
  }

  // ---- Pb stores issued last (overlap next block's DMA phase) ----
  unsigned short* prow = Pb + (((size_t)(b * 16 + h)) * 256 + q0 + fr) * 256 + grp * 4;
  #pragma unroll
  for (int nf = 0; nf < 16; ++nf)
    *(uint2*)(prow + nf * 16) = u2[nf];
}

// attm[b][q][k] = (1/16) sum_h Pb[b][h][q][k]
__global__ __launch_bounds__(256) void attm_reduce(
    const unsigned short* __restrict__ Pb, float* __restrict__ attm)
{
  const size_t idx = (size_t)blockIdx.x * 256 + threadIdx.x;
  const int    k8  = (int)(idx & 31);
  const size_t bq  = idx >> 5;
  const int    b   = (int)(bq >> 8);
  const int    q   = (int)(bq & 255);
  float s[8] = {};
  const unsigned short* base = Pb + (size_t)b * 1048576 + (size_t)q * 256 + k8 * 8;
  #pragma unroll
  for (int hh = 0; hh < 16; ++hh) {
    const u16x8 p = *(const u16x8*)(base + (size_t)hh * 65536);
    #pragma unroll
    for (int j = 0; j < 8; ++j) s[j] += bf2f(p[j]);
  }
  float* dst = attm + bq * 256 + k8 * 8;
  float4 r0, r1;
  r0.x = s[0] * 0.0625f; r0.y = s[1] * 0.0625f; r0.z = s[2] * 0.0625f; r0.w = s[3] * 0.0625f;
  r1.x = s[4] * 0.0625f; r1.y = s[5] * 0.0625f; r1.z = s[6] * 0.0625f; r1.w = s[7] * 0.0625f;
  *(float4*)dst = r0;
  *(float4*)(dst + 4) = r1;
}

// ---------------------------------------------------------------
extern "C" void kernel_launch(void* const* d_in, const int* in_sizes, int n_in,
                              void* d_out, int out_size, void* d_ws, size_t ws_size,
                              hipStream_t stream)
{
  const float* obj   = (const float*)d_in[0];
  const float* cross = (const float*)d_in[1];
  const int*   adj   = (const int*)d_in[2];
  const float* lab   = (const float*)d_in[3];
  const float* Wq    = (const float*)d_in[4];
  const float* bq    = (const float*)d_in[5];
  const float* Wk    = (const float*)d_in[6];
  const float* bk    = (const float*)d_in[7];
  const float* Wv    = (const float*)d_in[8];
  const float* bv    = (const float*)d_in[9];
  const float* Wo    = (const float*)d_in[10];
  const float* bo    = (const float*)d_in[11];

  float* out  = (float*)d_out;
  float* attm = out + (size_t)16 * 256 * 1024;

  // workspace layout (bytes)
  char* ws = (char*)d_ws;
  unsigned short* obj_bf   = (unsigned short*)(ws + 0);          // 8 MB
  unsigned short* cross_bf = (unsigned short*)(ws + 8388608);    // 8 MB
  unsigned short* Qbf      = (unsigned short*)(ws + 16777216);   // 8 MB
  unsigned short* Kbf      = (unsigned short*)(ws + 25165824);   // 8 MB
  unsigned short* VWt      = (unsigned short*)(ws + 33554432);   // 8 MB [B*1024][256]
  unsigned short* Wall     = (unsigned short*)(ws + 41943040);   // 6 MB [3072][1024]
  unsigned short* Wo_bf    = (unsigned short*)(ws + 48234496);   // 2 MB
  unsigned short* Wvt_bf   = (unsigned short*)(ws + 50331648);   // 2 MB
  unsigned short* Pbuf     = (unsigned short*)(ws + 52432896);   // 32 MB (ends 85,987,328)

  const bool big_ws = ws_size >= (size_t)104857600;  // 100 MB

  if (big_ws) {
    float* ball = (float*)(ws + 92274688);           // 88 MiB, 12 KB
    float* mbuf = (float*)(ws + 96468992);           // 92 MiB, 4 MB
    prep_all<<<13572, 256, 0, stream>>>(
        obj, cross, Wq, Wk, Wo, Wv, bq, bk, bv, adj, lab,
        obj_bf, cross_bf, Wall, Wo_bf, Wvt_bf, ball, mbuf);
    gemm_wov<<<dim3(16, 16), 256, 0, stream>>>(Wo_bf, Wvt_bf, Wall + 2097152);
    gemm_big<<<192, 512, 0, stream>>>(obj_bf, cross_bf, Wall, ball, Qbf, Kbf, VWt);
    attn_mfma<<<512, 512, 0, stream>>>(Qbf, Kbf, VWt, mbuf, bo, out, Pbuf);
    attm_reduce<<<512, 256, 0, stream>>>(Pbuf, attm);
  } else {
    float* ball = (float*)(ws + 50331648);           // aliases Wvt_bf (write after wov)
    float* mbuf = (float*)obj_bf;                    // aliases obj_bf (write after gemm_big)
    cvt2_bf16<<<8192, 256, 0, stream>>>(obj, cross, obj_bf, cross_bf);
    prep_w<<<4096, 256, 0, stream>>>(Wq, Wk, Wo, Wv, Wall, Wo_bf, Wvt_bf);
    gemm_wov<<<dim3(16, 16), 256, 0, stream>>>(Wo_bf, Wvt_bf, Wall + 2097152);
    prep_bias<<<260, 256, 0, stream>>>(bq, bk, Wo, bv, ball);
    gemm_big<<<192, 512, 0, stream>>>(obj_bf, cross_bf, Wall, ball, Qbf, Kbf, VWt);
    mb_prep<<<1024, 256, 0, stream>>>(adj, lab, mbuf);
    attn_mfma<<<512, 512, 0, stream>>>(Qbf, Kbf, VWt, mbuf, bo, out, Pbuf);
    attm_reduce<<<512, 256, 0, stream>>>(Pbuf, attm);
  }
}

// Round 16
// 103.996 us; speedup vs baseline: 1.0341x; 1.0341x over previous
//
#include <hip/hip_runtime.h>

#define NEGF -9e15f

typedef __attribute__((ext_vector_type(8))) unsigned short u16x8;
typedef __attribute__((ext_vector_type(8))) short          s16x8;
typedef __attribute__((ext_vector_type(4))) float          f32x4;

// ---------- bf16 helpers (RTN-even) ----------
__device__ __forceinline__ unsigned short f2bf(float x) {
  union { float f; unsigned int u; } c; c.f = x;
  unsigned int r = c.u + 0x7fffu + ((c.u >> 16) & 1u);
  return (unsigned short)(r >> 16);
}
__device__ __forceinline__ float bf2f(unsigned short v) {
  union { float f; unsigned int u; } c; c.u = ((unsigned int)v) << 16;
  return c.f;
}

// ---------- async global->LDS, 16B per lane (wave-uniform LDS base) ----------
__device__ __forceinline__ void gload16(const void* g, void* l) {
  __builtin_amdgcn_global_load_lds(
      (const __attribute__((address_space(1))) unsigned int*)g,
      (__attribute__((address_space(3))) unsigned int*)l, 16, 0, 0);
}

// ================= prep kernels (fallback path) =================
__global__ __launch_bounds__(256) void cvt2_bf16(
    const float* __restrict__ a, const float* __restrict__ b,
    unsigned short* __restrict__ oa, unsigned short* __restrict__ ob)
{
  const int bid = blockIdx.x;
  const float* in = (bid < 4096) ? a : b;
  unsigned short* out = (bid < 4096) ? oa : ob;
  const int i = ((bid & 4095) * 256 + threadIdx.x) * 4;
  const float4 v = *(const float4*)(in + i);
  ushort4 o;
  o.x = f2bf(v.x); o.y = f2bf(v.y); o.z = f2bf(v.z); o.w = f2bf(v.w);
  *(ushort4*)(out + i) = o;
}

__global__ __launch_bounds__(256) void prep_w(
    const float* __restrict__ Wq, const float* __restrict__ Wk,
    const float* __restrict__ Wo, const float* __restrict__ Wv,
    unsigned short* __restrict__ Wall, unsigned short* __restrict__ Wo_bf,
    unsigned short* __restrict__ Wvt_bf)
{
  __shared__ float tile[32][33];
  const int bid = blockIdx.x;
  if (bid < 3072) {
    const int i = ((bid & 1023) * 256 + threadIdx.x) * 4;
    const float* in;
    unsigned short* out;
    float sc = 1.f;
    if (bid < 1024)      { in = Wq; out = Wall;           sc = 0.125f; }
    else if (bid < 2048) { in = Wk; out = Wall + 1048576; }
    else                 { in = Wo; out = Wo_bf; }
    const float4 v = *(const float4*)(in + i);
    ushort4 o;
    o.x = f2bf(v.x * sc); o.y = f2bf(v.y * sc);
    o.z = f2bf(v.z * sc); o.w = f2bf(v.w * sc);
    *(ushort4*)(out + i) = o;
  } else {
    const int j = bid - 3072;
    const int bc = (j & 31) * 32, br = (j >> 5) * 32;
    const int tx = threadIdx.x & 31, ty8 = threadIdx.x >> 5;
    #pragma unroll
    for (int jj = 0; jj < 32; jj += 8)
      tile[ty8 + jj][tx] = Wv[(size_t)(br + ty8 + jj) * 1024 + bc + tx];
    __syncthreads();
    #pragma unroll
    for (int jj = 0; jj < 32; jj += 8)
      Wvt_bf[(size_t)(bc + ty8 + jj) * 1024 + br + tx] = f2bf(tile[tx][ty8 + jj]);
  }
}

__global__ __launch_bounds__(256) void prep_bias(
    const float* __restrict__ bq, const float* __restrict__ bk,
    const float* __restrict__ Wo, const float* __restrict__ bv,
    float* __restrict__ ball)
{
  const int bid = blockIdx.x;
  if (bid < 4) {
    const int i = bid * 256 + threadIdx.x;
    ball[i]        = 0.125f * bq[i];
    ball[1024 + i] = bk[i];
  } else {
    const int g    = (bid - 4) * 4 + (threadIdx.x >> 6);
    const int lane = threadIdx.x & 63;
    float acc = 0.f;
    for (int f = lane; f < 1024; f += 64)
      acc = fmaf(Wo[(size_t)g * 1024 + f], bv[f], acc);
    #pragma unroll
    for (int off = 32; off > 0; off >>= 1) acc += __shfl_down(acc, off);
    if (lane == 0) ball[2048 + g] = acc;
  }
}

__global__ __launch_bounds__(256) void mb_prep(
    const int* __restrict__ adj, const float* __restrict__ lab,
    float* __restrict__ mb)
{
  const int i = (blockIdx.x * 256 + threadIdx.x) * 4;
  const int4   a = *(const int4*)(adj + i);
  const float4 l = *(const float4*)(lab + i);
  float4 o;
  o.x = a.x > 0 ? l.x : NEGF;
  o.y = a.y > 0 ? l.y : NEGF;
  o.z = a.z > 0 ? l.z : NEGF;
  o.w = a.w > 0 ? l.w : NEGF;
  *(float4*)(mb + i) = o;
}

// ================= fused prep (big-ws path) =================
__global__ __launch_bounds__(256) void prep_all(
    const float* __restrict__ obj, const float* __restrict__ cross,
    const float* __restrict__ Wq, const float* __restrict__ Wk,
    const float* __restrict__ Wo, const float* __restrict__ Wv,
    const float* __restrict__ bq, const float* __restrict__ bk,
    const float* __restrict__ bv,
    const int* __restrict__ adj, const float* __restrict__ lab,
    unsigned short* __restrict__ obj_bf, unsigned short* __restrict__ cross_bf,
    unsigned short* __restrict__ Wall, unsigned short* __restrict__ Wo_bf,
    unsigned short* __restrict__ Wvt_bf,
    float* __restrict__ ball, float* __restrict__ mb)
{
  __shared__ float tile[32][33];
  const int bid = blockIdx.x;
  if (bid < 8192) {
    const float* in = (bid < 4096) ? obj : cross;
    unsigned short* out = (bid < 4096) ? obj_bf : cross_bf;
    const int i = ((bid & 4095) * 256 + threadIdx.x) * 4;
    const float4 v = *(const float4*)(in + i);
    ushort4 o;
    o.x = f2bf(v.x); o.y = f2bf(v.y); o.z = f2bf(v.z); o.w = f2bf(v.w);
    *(ushort4*)(out + i) = o;
  } else if (bid < 11264) {
    const int wb = bid - 8192;
    const int i = ((wb & 1023) * 256 + threadIdx.x) * 4;
    const float* in;
    unsigned short* out;
    float sc = 1.f;
    if (wb < 1024)      { in = Wq; out = Wall;           sc = 0.125f; }
    else if (wb < 2048) { in = Wk; out = Wall + 1048576; }
    else                { in = Wo; out = Wo_bf; }
    const float4 v = *(const float4*)(in + i);
    ushort4 o;
    o.x = f2bf(v.x * sc); o.y = f2bf(v.y * sc);
    o.z = f2bf(v.z * sc); o.w = f2bf(v.w * sc);
    *(ushort4*)(out + i) = o;
  } else if (bid < 12288) {
    const int j = bid - 11264;
    const int bc = (j & 31) * 32, br = (j >> 5) * 32;
    const int tx = threadIdx.x & 31, ty8 = threadIdx.x >> 5;
    #pragma unroll
    for (int jj = 0; jj < 32; jj += 8)
      tile[ty8 + jj][tx] = Wv[(size_t)(br + ty8 + jj) * 1024 + bc + tx];
    __syncthreads();
    #pragma unroll
    for (int jj = 0; jj < 32; jj += 8)
      Wvt_bf[(size_t)(bc + ty8 + jj) * 1024 + br + tx] = f2bf(tile[tx][ty8 + jj]);
  } else if (bid < 12548) {
    const int pb = bid - 12288;
    if (pb < 4) {
      const int i = pb * 256 + threadIdx.x;
      ball[i]        = 0.125f * bq[i];
      ball[1024 + i] = bk[i];
    } else {
      const int g    = (pb - 4) * 4 + (threadIdx.x >> 6);
      const int lane = threadIdx.x & 63;
      float acc = 0.f;
      for (int f = lane; f < 1024; f += 64)
        acc = fmaf(Wo[(size_t)g * 1024 + f], bv[f], acc);
      #pragma unroll
      for (int off = 32; off > 0; off >>= 1) acc += __shfl_down(acc, off);
      if (lane == 0) ball[2048 + g] = acc;
    }
  } else {
    const int i = ((bid - 12548) * 256 + threadIdx.x) * 4;
    const int4   a = *(const int4*)(adj + i);
    const float4 l = *(const float4*)(lab + i);
    float4 o;
    o.x = a.x > 0 ? l.x : NEGF;
    o.y = a.y > 0 ? l.y : NEGF;
    o.z = a.z > 0 ? l.z : NEGF;
    o.w = a.w > 0 ? l.w : NEGF;
    *(float4*)(mb + i) = o;
  }
}

// ---------------------------------------------------------------
// Wov = Wo @ Wv (1024^3), m97-style staging, 64x64 tiles -> 256 blocks.
// ---------------------------------------------------------------
__global__ __launch_bounds__(256, 3) void gemm_wov(
    const unsigned short* __restrict__ A,
    const unsigned short* __restrict__ Bw,
    unsigned short* __restrict__ Cout)
{
  __shared__ unsigned short Asm[64 * 64];
  __shared__ unsigned short Bsm[64 * 64];
  const int t = threadIdx.x;
  const int lane = t & 63, w = t >> 6;
  const int wm = w >> 1, wn = w & 1;
  const int bm = blockIdx.y * 64, bn = blockIdx.x * 64;

  const int skel = (lane & 7) * 8;
  const int fr = lane & 15, kf = (lane >> 4) * 8;

  f32x4 acc[2][2] = {};

  for (int k0 = 0; k0 < 1024; k0 += 64) {
    if (k0) __syncthreads();
    #pragma unroll
    for (int c = 0; c < 2; ++c) {
      const int row = c * 32 + w * 8 + (lane >> 3);
      gload16(A  + (size_t)(bm + row) * 1024 + k0 + skel, (char*)Asm + c * 4096 + w * 1024);
      gload16(Bw + (size_t)(bn + row) * 1024 + k0 + skel, (char*)Bsm + c * 4096 + w * 1024);
    }
    __syncthreads();
    #pragma unroll
    for (int kk = 0; kk < 2; ++kk) {
      s16x8 af[2], bf[2];
      #pragma unroll
      for (int fm = 0; fm < 2; ++fm)
        af[fm] = *(const s16x8*)&Asm[(wm * 32 + fm * 16 + fr) * 64 + kk * 32 + kf];
      #pragma unroll
      for (int fn = 0; fn < 2; ++fn)
        bf[fn] = *(const s16x8*)&Bsm[(wn * 32 + fn * 16 + fr) * 64 + kk * 32 + kf];
      #pragma unroll
      for (int fm = 0; fm < 2; ++fm)
        #pragma unroll
        for (int fn = 0; fn < 2; ++fn)
          acc[fm][fn] = __builtin_amdgcn_mfma_f32_16x16x32_bf16(af[fm], bf[fn], acc[fm][fn], 0, 0, 0);
    }
  }

  const int rg = (lane >> 4) * 4;
  #pragma unroll
  for (int fm = 0; fm < 2; ++fm)
    #pragma unroll
    for (int fn = 0; fn < 2; ++fn) {
      const int col = bn + wn * 32 + fn * 16 + fr;
      #pragma unroll
      for (int r = 0; r < 4; ++r) {
        const int row = bm + wm * 32 + fm * 16 + rg + r;
        Cout[(size_t)row * 1024 + col] = f2bf(acc[fm][fn][r]);
      }
    }
}

// ---------------------------------------------------------------
// Fused projection GEMM v3 + coalesced LDS-bounce epilogue (r14-identical).
// ---------------------------------------------------------------
__global__ __launch_bounds__(512, 2) void gemm_big(
    const unsigned short* __restrict__ objA,
    const unsigned short* __restrict__ crossA,
    const unsigned short* __restrict__ Wall,   // [3072][1024]
    const float* __restrict__ ball,            // [3072]
    unsigned short* __restrict__ Qo,           // [4096][1024]
    unsigned short* __restrict__ Ko,           // [4096][1024]
    unsigned short* __restrict__ VWt)          // [B*1024][256]
{
  __shared__ __align__(16) char smem[131072];
  const int t = threadIdx.x;
  const int wid = t >> 6, lane = t & 63;
  const int wm = wid >> 2, wn = wid & 3;
  const int fr = lane & 15, grp = lane >> 4;

  const int bid = blockIdx.x;
  const int xcd = bid & 7, j = bid >> 3;
  const int bmi = (xcd >> 1) * 4 + j / 6;
  const int bni = (xcd & 1) * 6 + j % 6;
  const int bm = bmi * 256, bn = bni * 256;
  const unsigned short* Ag = ((bni < 4) ? objA : crossA) + (size_t)bm * 1024;
  const unsigned short* Bg = Wall + (size_t)bn * 1024;

  const int r8 = lane >> 3, cb = (lane & 7) * 16;

  f32x4 acc[8][4] = {};
  s16x8 bfr[4][2];
  s16x8 aq[2][2];

  auto CH = [&](int buf, int isB, int q, int k0) {
    const int row = q * 64 + wid * 8 + r8;
    const int sc  = cb ^ ((row & 7) << 4);
    const unsigned short* src = isB ? Bg : Ag;
    gload16((const char*)(src + (size_t)row * 1024 + k0) + sc,
            smem + buf * 65536 + isB * 32768 + q * 8192 + wid * 1024);
  };

#define BAR() { asm volatile("" ::: "memory"); __builtin_amdgcn_s_barrier(); asm volatile("" ::: "memory"); }
#define RDB(BUF)                                                             \
  { _Pragma("unroll") for (int fn = 0; fn < 4; ++fn)                         \
      _Pragma("unroll") for (int kk = 0; kk < 2; ++kk) {                     \
        const int row = wn * 64 + fn * 16 + fr;                              \
        bfr[fn][kk] = *(const s16x8*)((BUF) + 32768 + row * 128 +            \
            ((kk * 64 + grp * 16) ^ ((row & 7) << 4)));                      \
      } }
#define RDA(BUF, P)                                                          \
  { _Pragma("unroll") for (int fm = 0; fm < 2; ++fm)                         \
      _Pragma("unroll") for (int kk = 0; kk < 2; ++kk) {                     \
        const int row = wm * 128 + (2 * (P) + fm) * 16 + fr;                 \
        aq[fm][kk] = *(const s16x8*)((BUF) + row * 128 +                     \
            ((kk * 64 + grp * 16) ^ ((row & 7) << 4)));                      \
      } }
#define MMQ(P)                                                               \
  { __builtin_amdgcn_s_setprio(1);                                           \
    _Pragma("unroll") for (int fm = 0; fm < 2; ++fm)                         \
      _Pragma("unroll") for (int fn = 0; fn < 4; ++fn) {                     \
        acc[2 * (P) + fm][fn] = __builtin_amdgcn_mfma_f32_16x16x32_bf16(     \
            aq[fm][0], bfr[fn][0], acc[2 * (P) + fm][fn], 0, 0, 0);          \
        acc[2 * (P) + fm][fn] = __builtin_amdgcn_mfma_f32_16x16x32_bf16(     \
            aq[fm][1], bfr[fn][1], acc[2 * (P) + fm][fn], 0, 0, 0);          \
      }                                                                      \
    __builtin_amdgcn_s_setprio(0); }
#define TILE4(BUF)                                                           \
  RDB(BUF); RDA(BUF, 0); BAR(); MMQ(0); BAR();                               \
  RDA(BUF, 1); BAR(); MMQ(1); BAR();                                         \
  RDA(BUF, 2); BAR(); MMQ(2); BAR();                                         \
  RDA(BUF, 3); BAR(); MMQ(3); BAR();

  CH(0, 1, 0, 0); CH(0, 1, 1, 0); CH(0, 1, 2, 0); CH(0, 1, 3, 0);
  CH(0, 0, 0, 0); CH(0, 0, 1, 0); CH(0, 0, 2, 0); CH(0, 0, 3, 0);
  CH(1, 1, 0, 64); CH(1, 1, 1, 64); CH(1, 1, 2, 64); CH(1, 1, 3, 64);
  CH(1, 0, 0, 64); CH(1, 0, 2, 64);

  #pragma unroll 2
  for (int kt = 0; kt < 14; ++kt) {
    const int cur = kt & 1;
    char* bufc = smem + cur * 65536;
    const int k1 = (kt + 1) * 64, k2 = (kt + 2) * 64;
    CH(cur ^ 1, 0, 1, k1);
    CH(cur ^ 1, 0, 3, k1);
    asm volatile("s_waitcnt vmcnt(8)" ::: "memory");
    BAR();
    RDB(bufc); RDA(bufc, 0);
    BAR(); MMQ(0); BAR();
    RDA(bufc, 1); CH(cur, 1, 0, k2); CH(cur, 1, 1, k2);
    BAR(); MMQ(1); BAR();
    RDA(bufc, 2); CH(cur, 1, 2, k2); CH(cur, 1, 3, k2);
    BAR(); MMQ(2); BAR();
    RDA(bufc, 3); CH(cur, 0, 0, k2); CH(cur, 0, 2, k2);
    BAR(); MMQ(3); BAR();
  }
  CH(1, 0, 1, 960); CH(1, 0, 3, 960);
  asm volatile("s_waitcnt vmcnt(8)" ::: "memory");
  BAR();
  TILE4(smem);
  asm volatile("s_waitcnt vmcnt(0)" ::: "memory");
  BAR();
  TILE4(smem + 65536);

#undef BAR
#undef RDB
#undef RDA
#undef MMQ
#undef TILE4

  // ---- epilogue: acc -> bf16 LDS image (swizzled) -> coalesced 16B stores ----
  __syncthreads();
  const int rg = grp * 4;
  const int mode = bn >> 10;                           // 0=Q 1=K 2=VW
  if (mode < 2) {
    #pragma unroll
    for (int fm = 0; fm < 8; ++fm)
      #pragma unroll
      for (int fn = 0; fn < 4; ++fn) {
        const int col = wn * 64 + fn * 16 + fr;
        const float bb = ball[bn + col];
        const int row0 = wm * 128 + fm * 16 + rg;
        #pragma unroll
        for (int r = 0; r < 4; ++r)
          *(unsigned short*)(smem + (row0 + r) * 512 +
              ((col * 2) ^ (((row0 + r) & 7) << 4))) = f2bf(acc[fm][fn][r] + bb);
      }
    __syncthreads();
    unsigned short* dst0 = (mode == 0) ? Qo : Ko;
    #pragma unroll
    for (int it = 0; it < 16; ++it) {
      const int row = it * 16 + wid * 2 + (lane >> 5);
      const int off = (lane & 31) * 16;
      *(u16x8*)((char*)(dst0 + (size_t)(bm + row) * 1024 + (bn & 1023)) + off)
          = *(const u16x8*)(smem + row * 512 + (off ^ ((row & 7) << 4)));
    }
  } else {
    #pragma unroll
    for (int fm = 0; fm < 8; ++fm)
      #pragma unroll
      for (int fn = 0; fn < 4; ++fn) {
        const int col = wn * 64 + fn * 16 + fr;
        const float bb = ball[bn + col];
        const int tok0 = wm * 128 + fm * 16 + rg;
        ushort4 u;
        u.x = f2bf(acc[fm][fn][0] + bb);
        u.y = f2bf(acc[fm][fn][1] + bb);
        u.z = f2bf(acc[fm][fn][2] + bb);
        u.w = f2bf(acc[fm][fn][3] + bb);
        *(ushort4*)(smem + col * 512 + ((tok0 * 2) ^ ((col & 7) << 4))) = u;
      }
    __syncthreads();
    const int bidx = bm >> 8;
    #pragma unroll
    for (int it = 0; it < 16; ++it) {
      const int col = it * 16 + wid * 2 + (lane >> 5);
      const int off = (lane & 31) * 16;
      *(u16x8*)((char*)(VWt + ((size_t)bidx * 1024 + (bn & 1023) + col) * 256) + off)
          = *(const u16x8*)(smem + col * 512 + (off ^ ((col & 7) << 4)));
    }
  }
}

// ---------------------------------------------------------------
// MFMA attention v6 (r14-identical — r15's setprio + late-Pb reverted:
// late Pb stores broke write-combining, WRITE_SIZE 53->72 MB, +3.4 us).
// ---------------------------------------------------------------
__global__ __launch_bounds__(512, 4) void attn_mfma(
    const unsigned short* __restrict__ Qg,    // [B*256][1024] bf16, pre-scaled 1/8
    const unsigned short* __restrict__ Kg,    // [B*256][1024] bf16
    const unsigned short* __restrict__ VWt,   // [B*1024][256] bf16 ([b][h*64+d][k])
    const float* __restrict__ mb,             // [B][256][256] masked bias
    const float* __restrict__ bo,
    float* __restrict__ outp, unsigned short* __restrict__ Pb)
{
  const int t = threadIdx.x;
  const int wid = t >> 6, lane = t & 63;
  const int fr = lane & 15, grp = lane >> 4;
  const int bid = blockIdx.x;
  const int xcd = bid & 7, i = bid >> 3;     // i in [0,64)
  const int h    = i & 15;
  const int r2   = i >> 4;                   // [0,4)
  const int half = r2 & 1;
  const int b    = xcd * 2 + (r2 >> 1);
  const int q0 = half * 128 + wid * 16;

  __shared__ __align__(16) unsigned short Ks[256 * 64];    // 32 KB [k_row][d]
  __shared__ __align__(16) unsigned short VWs[64 * 256];   // 32 KB [d][k]

  // ---- DMA K slice (b,h) ----
  {
    const unsigned short* kb = Kg + (size_t)(b * 256) * 1024 + h * 64;
    const int colb = (lane & 7) * 16;
    #pragma unroll
    for (int c = 0; c < 4; ++c) {
      const int row = c * 64 + wid * 8 + (lane >> 3);
      const int sb  = colb ^ ((row & 7) << 4);
      gload16(kb + (size_t)row * 1024 + (sb >> 1), (char*)Ks + c * 8192 + wid * 1024);
    }
  }
  // ---- DMA VW slice (b,h) ----
  {
    const unsigned short* vwb = VWt + (size_t)(b * 16 + h) * 16384;
    const int xb = (lane & 31) * 16;
    #pragma unroll
    for (int c = 0; c < 4; ++c) {
      const int row = c * 16 + wid * 2 + (lane >> 5);
      const int sb  = xb ^ ((row & 7) << 4);
      gload16(vwb + row * 256 + (sb >> 1), (char*)VWs + c * 8192 + wid * 1024);
    }
  }

  // ---- Q B-frags + first mb batch (overlap DMA drain) ----
  const unsigned short* qp = Qg + ((size_t)(b * 256 + q0 + fr)) * 1024 + h * 64 + grp * 8;
  const s16x8 qf0 = *(const s16x8*)qp;
  const s16x8 qf1 = *(const s16x8*)(qp + 32);
  const float* mbp = mb + ((size_t)(b * 256 + q0 + fr)) * 256 + grp * 4;
  float4 mA[4], mB[4];
  #pragma unroll
  for (int i2 = 0; i2 < 4; ++i2) mA[i2] = *(const float4*)(mbp + i2 * 16);

  __syncthreads();   // drains DMA (vmcnt 0) -> Ks/VWs ready

  const int colA = (grp * 16) ^ ((fr & 7) << 4);

  f32x4 s[16];
  #pragma unroll
  for (int nf = 0; nf < 16; ++nf) s[nf] = (f32x4){0.f, 0.f, 0.f, 0.f};

  s16x8 kA[8], kB[8];
  float mx = -3e38f;

#define LOADK(KF, nb)                                                        \
  { _Pragma("unroll") for (int i2 = 0; i2 < 4; ++i2) {                       \
      const char* rp = (const char*)Ks + (((nb)*4 + i2) * 16 + fr) * 128;    \
      KF[2*i2]   = *(const s16x8*)(rp + colA);                               \
      KF[2*i2+1] = *(const s16x8*)(rp + (colA ^ 64)); } }
#define LOADB(KF, MF, nb)                                                    \
  { _Pragma("unroll") for (int i2 = 0; i2 < 4; ++i2) {                       \
      const char* rp = (const char*)Ks + (((nb)*4 + i2) * 16 + fr) * 128;    \
      KF[2*i2]   = *(const s16x8*)(rp + colA);                               \
      KF[2*i2+1] = *(const s16x8*)(rp + (colA ^ 64));                        \
      MF[i2]     = *(const float4*)(mbp + ((nb)*4 + i2) * 16); } }
#define MFMAB(KF, nb)                                                        \
  { _Pragma("unroll") for (int i2 = 0; i2 < 4; ++i2) {                       \
      s[(nb)*4+i2] = __builtin_amdgcn_mfma_f32_16x16x32_bf16(KF[2*i2],   qf0, s[(nb)*4+i2], 0, 0, 0); \
      s[(nb)*4+i2] = __builtin_amdgcn_mfma_f32_16x16x32_bf16(KF[2*i2+1], qf1, s[(nb)*4+i2], 0, 0, 0); } }
#define MASKB(MF, nb)                                                        \
  { _Pragma("unroll") for (int i2 = 0; i2 < 4; ++i2) {                       \
      _Pragma("unroll") for (int r = 0; r < 4; ++r) {                        \
        const float m = ((const float*)&MF[i2])[r];                          \
        const float v = (m > -1e14f) ? s[(nb)*4+i2][r] + m : m;              \
        s[(nb)*4+i2][r] = v; mx = fmaxf(mx, v); } } }

  LOADK(kA, 0);     LOADB(kB, mB, 1); MFMAB(kA, 0);
  MASKB(mA, 0);     LOADB(kA, mA, 2); MFMAB(kB, 1);
  MASKB(mB, 1);     LOADB(kB, mB, 3); MFMAB(kA, 2);
  MASKB(mA, 2);     LOADB(kA, mA, 4); MFMAB(kB, 3);
  MASKB(mB, 3);     LOADB(kB, mB, 5); MFMAB(kA, 4);
  MASKB(mA, 4);     LOADB(kA, mA, 6); MFMAB(kB, 5);
  MASKB(mB, 5);     LOADB(kB, mB, 7); MFMAB(kA, 6);
  MASKB(mA, 6);     MFMAB(kB, 7);     MASKB(mB, 7);
#undef LOADK
#undef LOADB
#undef MFMAB
#undef MASKB

  // ---- softmax ----
  mx = fmaxf(mx, __shfl_xor(mx, 16));
  mx = fmaxf(mx, __shfl_xor(mx, 32));
  float sm = 0.f;
  #pragma unroll
  for (int nf = 0; nf < 16; ++nf)
    #pragma unroll
    for (int r = 0; r < 4; ++r) {
      const float e = __expf(s[nf][r] - mx);
      s[nf][r] = e;
      sm += e;
    }
  sm += __shfl_xor(sm, 16);
  sm += __shfl_xor(sm, 32);
  const float inv = 1.f / sm;

  // ---- pack P -> bf16 pairs ----
  uint2 u2[16];
  #pragma unroll
  for (int nf = 0; nf < 16; ++nf) {
    const unsigned lo = (unsigned)f2bf(s[nf][0] * inv) | ((unsigned)f2bf(s[nf][1] * inv) << 16);
    const unsigned hi = (unsigned)f2bf(s[nf][2] * inv) | ((unsigned)f2bf(s[nf][3] * inv) << 16);
    u2[nf] = make_uint2(lo, hi);
  }

  // ---- Pb store (early — between softmax and PV; r14-proven placement) ----
  unsigned short* prow = Pb + (((size_t)(b * 16 + h)) * 256 + q0 + fr) * 256 + grp * 4;
  #pragma unroll
  for (int nf = 0; nf < 16; ++nf)
    *(uint2*)(prow + nf * 16) = u2[nf];

  // ---- PV ----
  f32x4 o[4];
  #pragma unroll
  for (int nf = 0; nf < 4; ++nf) o[nf] = (f32x4){0.f, 0.f, 0.f, 0.f};
  const int srcA = fr + ((grp & 1) << 5);
  const int srcB = srcA + 16;
  const int swz  = (fr & 7) << 4;
  const bool hiSel = (grp & 2);
  #pragma unroll
  for (int ks = 0; ks < 8; ++ks) {
    const int aLx = __shfl((int)u2[2 * ks].x,     srcA, 64);
    const int aLy = __shfl((int)u2[2 * ks].y,     srcA, 64);
    const int bLx = __shfl((int)u2[2 * ks].x,     srcB, 64);
    const int bLy = __shfl((int)u2[2 * ks].y,     srcB, 64);
    const int aHx = __shfl((int)u2[2 * ks + 1].x, srcA, 64);
    const int aHy = __shfl((int)u2[2 * ks + 1].y, srcA, 64);
    const int bHx = __shfl((int)u2[2 * ks + 1].x, srcB, 64);
    const int bHy = __shfl((int)u2[2 * ks + 1].y, srcB, 64);
    union { int4 i; s16x8 v; } pf;
    pf.i = hiSel ? make_int4(aHx, aHy, bHx, bHy) : make_int4(aLx, aLy, bLx, bLy);
    const int cbv = (ks * 64 + grp * 16) ^ swz;
    #pragma unroll
    for (int nf = 0; nf < 4; ++nf) {
      const s16x8 vf = *(const s16x8*)((const char*)VWs + (nf * 16 + fr) * 512 + cbv);
      o[nf] = __builtin_amdgcn_mfma_f32_16x16x32_bf16(pf.v, vf, o[nf], 0, 0, 0);
    }
  }

  // ---- epilogue ----
  #pragma unroll
  for (int nf = 0; nf < 4; ++nf) {
    const float bb = bo[h * 64 + nf * 16 + fr];
    #pragma unroll
    for (int r = 0; r < 4; ++r)
      outp[((size_t)b * 256 + q0 + grp * 4 + r) * 1024 + h * 64 + nf * 16 + fr]
          = o[nf][r] + bb;
  }
}

// attm[b][q][k] = (1/16) sum_h Pb[b][h][q][k]
__global__ __launch_bounds__(256) void attm_reduce(
    const unsigned short* __restrict__ Pb, float* __restrict__ attm)
{
  const size_t idx = (size_t)blockIdx.x * 256 + threadIdx.x;
  const int    k8  = (int)(idx & 31);
  const size_t bq  = idx >> 5;
  const int    b   = (int)(bq >> 8);
  const int    q   = (int)(bq & 255);
  float s[8] = {};
  const unsigned short* base = Pb + (size_t)b * 1048576 + (size_t)q * 256 + k8 * 8;
  #pragma unroll
  for (int hh = 0; hh < 16; ++hh) {
    const u16x8 p = *(const u16x8*)(base + (size_t)hh * 65536);
    #pragma unroll
    for (int j = 0; j < 8; ++j) s[j] += bf2f(p[j]);
  }
  float* dst = attm + bq * 256 + k8 * 8;
  float4 r0, r1;
  r0.x = s[0] * 0.0625f; r0.y = s[1] * 0.0625f; r0.z = s[2] * 0.0625f; r0.w = s[3] * 0.0625f;
  r1.x = s[4] * 0.0625f; r1.y = s[5] * 0.0625f; r1.z = s[6] * 0.0625f; r1.w = s[7] * 0.0625f;
  *(float4*)dst = r0;
  *(float4*)(dst + 4) = r1;
}

// ---------------------------------------------------------------
extern "C" void kernel_launch(void* const* d_in, const int* in_sizes, int n_in,
                              void* d_out, int out_size, void* d_ws, size_t ws_size,
                              hipStream_t stream)
{
  const float* obj   = (const float*)d_in[0];
  const float* cross = (const float*)d_in[1];
  const int*   adj   = (const int*)d_in[2];
  const float* lab   = (const float*)d_in[3];
  const float* Wq    = (const float*)d_in[4];
  const float* bq    = (const float*)d_in[5];
  const float* Wk    = (const float*)d_in[6];
  const float* bk    = (const float*)d_in[7];
  const float* Wv    = (const float*)d_in[8];
  const float* bv    = (const float*)d_in[9];
  const float* Wo    = (const float*)d_in[10];
  const float* bo    = (const float*)d_in[11];

  float* out  = (float*)d_out;
  float* attm = out + (size_t)16 * 256 * 1024;

  // workspace layout (bytes)
  char* ws = (char*)d_ws;
  unsigned short* obj_bf   = (unsigned short*)(ws + 0);          // 8 MB
  unsigned short* cross_bf = (unsigned short*)(ws + 8388608);    // 8 MB
  unsigned short* Qbf      = (unsigned short*)(ws + 16777216);   // 8 MB
  unsigned short* Kbf      = (unsigned short*)(ws + 25165824);   // 8 MB
  unsigned short* VWt      = (unsigned short*)(ws + 33554432);   // 8 MB [B*1024][256]
  unsigned short* Wall     = (unsigned short*)(ws + 41943040);   // 6 MB [3072][1024]
  unsigned short* Wo_bf    = (unsigned short*)(ws + 48234496);   // 2 MB
  unsigned short* Wvt_bf   = (unsigned short*)(ws + 50331648);   // 2 MB
  unsigned short* Pbuf     = (unsigned short*)(ws + 52432896);   // 32 MB (ends 85,987,328)

  const bool big_ws = ws_size >= (size_t)104857600;  // 100 MB

  if (big_ws) {
    float* ball = (float*)(ws + 92274688);           // 88 MiB, 12 KB
    float* mbuf = (float*)(ws + 96468992);           // 92 MiB, 4 MB
    prep_all<<<13572, 256, 0, stream>>>(
        obj, cross, Wq, Wk, Wo, Wv, bq, bk, bv, adj, lab,
        obj_bf, cross_bf, Wall, Wo_bf, Wvt_bf, ball, mbuf);
    gemm_wov<<<dim3(16, 16), 256, 0, stream>>>(Wo_bf, Wvt_bf, Wall + 2097152);
    gemm_big<<<192, 512, 0, stream>>>(obj_bf, cross_bf, Wall, ball, Qbf, Kbf, VWt);
    attn_mfma<<<512, 512, 0, stream>>>(Qbf, Kbf, VWt, mbuf, bo, out, Pbuf);
    attm_reduce<<<512, 256, 0, stream>>>(Pbuf, attm);
  } else {
    float* ball = (float*)(ws + 50331648);           // aliases Wvt_bf (write after wov)
    float* mbuf = (float*)obj_bf;                    // aliases obj_bf (write after gemm_big)
    cvt2_bf16<<<8192, 256, 0, stream>>>(obj, cross, obj_bf, cross_bf);
    prep_w<<<4096, 256, 0, stream>>>(Wq, Wk, Wo, Wv, Wall, Wo_bf, Wvt_bf);
    gemm_wov<<<dim3(16, 16), 256, 0, stream>>>(Wo_bf, Wvt_bf, Wall + 2097152);
    prep_bias<<<260, 256, 0, stream>>>(bq, bk, Wo, bv, ball);
    gemm_big<<<192, 512, 0, stream>>>(obj_bf, cross_bf, Wall, ball, Qbf, Kbf, VWt);
    mb_prep<<<1024, 256, 0, stream>>>(adj, lab, mbuf);
    attn_mfma<<<512, 512, 0, stream>>>(Qbf, Kbf, VWt, mbuf, bo, out, Pbuf);
    attm_reduce<<<512, 256, 0, stream>>>(Pbuf, attm);
  }
}